// Round 1
// baseline (5822.629 us; speedup 1.0000x reference)
//
#include <hip/hip_runtime.h>

typedef _Float16 half_t;
typedef _Float16 half2_t __attribute__((ext_vector_type(2)));
typedef _Float16 half4_t __attribute__((ext_vector_type(4)));
typedef _Float16 half8_t __attribute__((ext_vector_type(8)));

#define S_LEN 4096
#define NB 4
#define H_DIM 1024

// ---------------------------------------------------------------------------
// Kernel 1: QKV projection.  C = x @ W + b, fp32 accumulate, fp16 store.
// q is pre-scaled by 1/sqrt(H) = 1/32 (power of 2 -> exact in fp16).
// 128x128 tile, 8x8 micro-tile, K-step 16, 256 threads.
// ---------------------------------------------------------------------------
#define G_TILE 128
#define G_KSTEP 16

__global__ __launch_bounds__(256, 4) void qkv_gemm(
    const float* __restrict__ x,
    const float* __restrict__ Wq, const float* __restrict__ bq,
    const float* __restrict__ Wk, const float* __restrict__ bk,
    const float* __restrict__ Wv, const float* __restrict__ bv,
    half_t* __restrict__ ws) {
  const int zi = blockIdx.z;
  const float* W = (zi == 0) ? Wq : (zi == 1) ? Wk : Wv;
  const float* bias = (zi == 0) ? bq : (zi == 1) ? bk : bv;
  half_t* out = ws + (size_t)zi * ((size_t)NB * S_LEN * H_DIM);
  const float oscale = (zi == 0) ? 0.03125f : 1.0f;
  const int n0 = blockIdx.x * G_TILE;
  const int m0 = blockIdx.y * G_TILE;
  const int t = threadIdx.x;

  __shared__ float As[G_KSTEP][G_TILE + 4];  // transposed: As[k][m]
  __shared__ float Bs[G_KSTEP][G_TILE + 4];

  float acc[8][8] = {};
  const int tm = (t >> 4) * 8;
  const int tn = (t & 15) * 8;

  for (int k0 = 0; k0 < 1024; k0 += G_KSTEP) {
    __syncthreads();  // protect LDS from previous iteration's readers
#pragma unroll
    for (int i = 0; i < 2; i++) {
      int flat = t * 4 + i * 1024;
      int mm = flat >> 4, kk = flat & 15;
      float4 av = *(const float4*)&x[(size_t)(m0 + mm) * 1024 + k0 + kk];
      As[kk + 0][mm] = av.x;
      As[kk + 1][mm] = av.y;
      As[kk + 2][mm] = av.z;
      As[kk + 3][mm] = av.w;
      int bkk = flat >> 7, bnn = flat & 127;
      *(float4*)&Bs[bkk][bnn] =
          *(const float4*)&W[(size_t)(k0 + bkk) * 1024 + n0 + bnn];
    }
    __syncthreads();
#pragma unroll
    for (int kk = 0; kk < G_KSTEP; kk++) {
      float4 a0 = *(const float4*)&As[kk][tm];
      float4 a1 = *(const float4*)&As[kk][tm + 4];
      float4 b0 = *(const float4*)&Bs[kk][tn];
      float4 b1 = *(const float4*)&Bs[kk][tn + 4];
      float av[8] = {a0.x, a0.y, a0.z, a0.w, a1.x, a1.y, a1.z, a1.w};
      float bv8[8] = {b0.x, b0.y, b0.z, b0.w, b1.x, b1.y, b1.z, b1.w};
#pragma unroll
      for (int i = 0; i < 8; i++)
#pragma unroll
        for (int j = 0; j < 8; j++)
          acc[i][j] = fmaf(av[i], bv8[j], acc[i][j]);
    }
  }

  float bb[8];
#pragma unroll
  for (int j = 0; j < 8; j++) bb[j] = bias[n0 + tn + j];
#pragma unroll
  for (int i = 0; i < 8; i++) {
    half8_t h;
#pragma unroll
    for (int j = 0; j < 8; j++) h[j] = (half_t)((acc[i][j] + bb[j]) * oscale);
    *(half8_t*)&out[(size_t)(m0 + tm + i) * 1024 + n0 + tn] = h;
  }
}

// ---------------------------------------------------------------------------
// Kernel 2: flash attention.  One block per (batch, 32 q-rows).
// Q tile fp16 in LDS, K streamed in fp16 chunks, scores via v_dot2_f32_f16
// (fp32 accum), online softmax (fp32), PV fp32 fmac with V from global.
// LDS ~78 KB, O in 128 VGPRs -> 2 blocks/CU.
// ---------------------------------------------------------------------------
#define TQ 32
#define TK 32
#define HC 128
#define QSTR 1032  // halves; row shift = 4 banks, 16B-aligned rows
#define KSTR 136   // halves
#define SSTR 36    // floats

__device__ __forceinline__ float fdot2_acc(half2_t a, half2_t b, float c) {
#if __has_builtin(__builtin_amdgcn_fdot2)
  return __builtin_amdgcn_fdot2(a, b, c, false);
#else
  return c + (float)a.x * (float)b.x + (float)a.y * (float)b.y;
#endif
}

union H8 {
  half8_t v;
  half2_t h2[4];
};

__global__ __launch_bounds__(256, 2) void flash_attn(
    const half_t* __restrict__ qw, const half_t* __restrict__ kw,
    const half_t* __restrict__ vw, float* __restrict__ out) {
  const int b = blockIdx.y;
  const int q0 = blockIdx.x * TQ;
  const int t = threadIdx.x;

  __shared__ half_t Qs[TQ * QSTR];
  __shared__ half_t Ks[TK * KSTR];
  __shared__ float Ss[TK * SSTR];  // [k][q], holds scores then P
  __shared__ float mS[TQ], lS[TQ], aS[TQ];

  const half_t* qb = qw + ((size_t)b * S_LEN + q0) * H_DIM;
  const half_t* kb = kw + (size_t)b * S_LEN * H_DIM;
  const half_t* vb = vw + (size_t)b * S_LEN * H_DIM;

  // stage Q tile (already pre-scaled by 1/32)
#pragma unroll
  for (int i = 0; i < 16; i++) {
    int flat = t * 8 + i * 2048;
    int r = flat >> 10, c = flat & 1023;
    *(half8_t*)&Qs[r * QSTR + c] = *(const half8_t*)&qb[(size_t)r * H_DIM + c];
  }
  if (t < TQ) {
    mS[t] = -1e30f;
    lS[t] = 0.0f;
  }
  float O[TQ][4] = {};

  const int tq = t >> 4;  // 0..15 -> q rows {tq, tq+16}
  const int tk = t & 15;  // 0..15 -> k rows {tk, tk+16}
  const int h4 = t * 4;   // this thread's 4 output columns

  for (int kt = 0; kt < S_LEN; kt += TK) {
    // ---- phase A: S[32][32] = Q . K^T (pre-scaled) ----
    float s00 = 0.f, s01 = 0.f, s10 = 0.f, s11 = 0.f;
    for (int hc = 0; hc < H_DIM; hc += HC) {
      __syncthreads();  // previous users of Ks / (iter0: Qs staging) done
#pragma unroll
      for (int i = 0; i < 2; i++) {
        int flat = t * 8 + i * 2048;
        int r = flat >> 7, c = flat & 127;
        *(half8_t*)&Ks[r * KSTR + c] =
            *(const half8_t*)&kb[(size_t)(kt + r) * H_DIM + hc + c];
      }
      __syncthreads();
#pragma unroll
      for (int c = 0; c < HC; c += 8) {
        H8 qa, qc, ka, kc;
        qa.v = *(const half8_t*)&Qs[tq * QSTR + hc + c];
        qc.v = *(const half8_t*)&Qs[(tq + 16) * QSTR + hc + c];
        ka.v = *(const half8_t*)&Ks[tk * KSTR + c];
        kc.v = *(const half8_t*)&Ks[(tk + 16) * KSTR + c];
#pragma unroll
        for (int j = 0; j < 4; j++) {
          s00 = fdot2_acc(qa.h2[j], ka.h2[j], s00);
          s01 = fdot2_acc(qa.h2[j], kc.h2[j], s01);
          s10 = fdot2_acc(qc.h2[j], ka.h2[j], s10);
          s11 = fdot2_acc(qc.h2[j], kc.h2[j], s11);
        }
      }
    }
    Ss[tk * SSTR + tq] = s00;
    Ss[(tk + 16) * SSTR + tq] = s01;
    Ss[tk * SSTR + (tq + 16)] = s10;
    Ss[(tk + 16) * SSTR + (tq + 16)] = s11;
    __syncthreads();

    // ---- phase B: online softmax stats (threads 0..31, one per q) ----
    if (t < TQ) {
      float m_old = mS[t];
      float mn = m_old;
#pragma unroll
      for (int k = 0; k < TK; k++) mn = fmaxf(mn, Ss[k * SSTR + t]);
      float al = __expf(m_old - mn);  // m_old=-1e30 -> exp(-huge)=0, no NaN
      float ls = 0.f;
#pragma unroll
      for (int k = 0; k < TK; k++) {
        float p = __expf(Ss[k * SSTR + t] - mn);
        Ss[k * SSTR + t] = p;
        ls += p;
      }
      mS[t] = mn;
      lS[t] = lS[t] * al + ls;
      aS[t] = al;
    }
    __syncthreads();

    // ---- rescale O by alpha[q] ----
#pragma unroll
    for (int q = 0; q < TQ; q++) {
      float al = aS[q];
      O[q][0] *= al;
      O[q][1] *= al;
      O[q][2] *= al;
      O[q][3] *= al;
    }

    // ---- phase C: O += P @ V (V fp16 from global, 1-deep prefetch) ----
    half4_t vcur = *(const half4_t*)&vb[(size_t)kt * H_DIM + h4];
#pragma unroll 4
    for (int k = 0; k < TK; k++) {
      int krow = kt + ((k + 1 < TK) ? (k + 1) : k);  // clamped prefetch
      half4_t vnext = *(const half4_t*)&vb[(size_t)krow * H_DIM + h4];
      float va[4] = {(float)vcur[0], (float)vcur[1], (float)vcur[2],
                     (float)vcur[3]};
#pragma unroll
      for (int q4 = 0; q4 < TQ; q4 += 4) {
        float4 p4 = *(const float4*)&Ss[k * SSTR + q4];
        float pv[4] = {p4.x, p4.y, p4.z, p4.w};
#pragma unroll
        for (int jj = 0; jj < 4; jj++)
#pragma unroll
          for (int m = 0; m < 4; m++)
            O[q4 + jj][m] = fmaf(pv[jj], va[m], O[q4 + jj][m]);
      }
      vcur = vnext;
    }
    // next iteration's first __syncthreads() protects Ss/Ks reuse
  }

  // ---- epilogue: normalize and store fp32 ----
#pragma unroll
  for (int q = 0; q < TQ; q++) {
    float inv = 1.0f / lS[q];
    float4 o = {O[q][0] * inv, O[q][1] * inv, O[q][2] * inv, O[q][3] * inv};
    *(float4*)&out[((size_t)b * S_LEN + q0 + q) * H_DIM + h4] = o;
  }
}

// ---------------------------------------------------------------------------
extern "C" void kernel_launch(void* const* d_in, const int* in_sizes, int n_in,
                              void* d_out, int out_size, void* d_ws,
                              size_t ws_size, hipStream_t stream) {
  const float* x = (const float*)d_in[0];
  const float* Wq = (const float*)d_in[1];
  const float* bq = (const float*)d_in[2];
  const float* Wk = (const float*)d_in[3];
  const float* bk = (const float*)d_in[4];
  const float* Wv = (const float*)d_in[5];
  const float* bv = (const float*)d_in[6];
  half_t* ws = (half_t*)d_ws;  // q(32MB) | k(32MB) | v(32MB), fp16
  float* out = (float*)d_out;

  qkv_gemm<<<dim3(H_DIM / G_TILE, (NB * S_LEN) / G_TILE, 3), 256, 0, stream>>>(
      x, Wq, bq, Wk, bk, Wv, bv, ws);

  const half_t* qw = ws;
  const half_t* kw = ws + (size_t)NB * S_LEN * H_DIM;
  const half_t* vw = ws + 2 * (size_t)NB * S_LEN * H_DIM;
  flash_attn<<<dim3(S_LEN / TQ, NB), 256, 0, stream>>>(qw, kw, vw, out);
}

// Round 2
// 2243.190 us; speedup vs baseline: 2.5957x; 2.5957x over previous
//
#include <hip/hip_runtime.h>

typedef _Float16 half_t;
typedef _Float16 half8_t __attribute__((ext_vector_type(8)));
typedef float float4_t __attribute__((ext_vector_type(4)));

#define S_LEN 4096
#define NB 4
#define H_DIM 1024

// ---------------------------------------------------------------------------
// Kernel 1: QKV projection.  C = x @ W + b, fp32 accumulate, fp16 store.
// q pre-scaled by 1/32 (exact). V stored TRANSPOSED: vt[b][h][s] so the
// attention kernel can read PV B-fragments as contiguous 16B loads.
// ---------------------------------------------------------------------------
#define G_TILE 128
#define G_KSTEP 16

__global__ __launch_bounds__(256, 4) void qkv_gemm(
    const float* __restrict__ x,
    const float* __restrict__ Wq, const float* __restrict__ bq,
    const float* __restrict__ Wk, const float* __restrict__ bk,
    const float* __restrict__ Wv, const float* __restrict__ bv,
    half_t* __restrict__ ws) {
  const int zi = blockIdx.z;
  const float* W = (zi == 0) ? Wq : (zi == 1) ? Wk : Wv;
  const float* bias = (zi == 0) ? bq : (zi == 1) ? bk : bv;
  half_t* out = ws + (size_t)zi * ((size_t)NB * S_LEN * H_DIM);
  const float oscale = (zi == 0) ? 0.03125f : 1.0f;
  const int n0 = blockIdx.x * G_TILE;
  const int m0 = blockIdx.y * G_TILE;
  const int t = threadIdx.x;

  __shared__ float As[G_KSTEP][G_TILE + 4];  // transposed: As[k][m]
  __shared__ float Bs[G_KSTEP][G_TILE + 4];

  float acc[8][8] = {};
  const int tm = (t >> 4) * 8;
  const int tn = (t & 15) * 8;

  for (int k0 = 0; k0 < 1024; k0 += G_KSTEP) {
    __syncthreads();
#pragma unroll
    for (int i = 0; i < 2; i++) {
      int flat = t * 4 + i * 1024;
      int mm = flat >> 4, kk = flat & 15;
      float4 av = *(const float4*)&x[(size_t)(m0 + mm) * 1024 + k0 + kk];
      As[kk + 0][mm] = av.x;
      As[kk + 1][mm] = av.y;
      As[kk + 2][mm] = av.z;
      As[kk + 3][mm] = av.w;
      int bkk = flat >> 7, bnn = flat & 127;
      *(float4*)&Bs[bkk][bnn] =
          *(const float4*)&W[(size_t)(k0 + bkk) * 1024 + n0 + bnn];
    }
    __syncthreads();
#pragma unroll
    for (int kk = 0; kk < G_KSTEP; kk++) {
      float4 a0 = *(const float4*)&As[kk][tm];
      float4 a1 = *(const float4*)&As[kk][tm + 4];
      float4 b0 = *(const float4*)&Bs[kk][tn];
      float4 b1 = *(const float4*)&Bs[kk][tn + 4];
      float av[8] = {a0.x, a0.y, a0.z, a0.w, a1.x, a1.y, a1.z, a1.w};
      float bv8[8] = {b0.x, b0.y, b0.z, b0.w, b1.x, b1.y, b1.z, b1.w};
#pragma unroll
      for (int i = 0; i < 8; i++)
#pragma unroll
        for (int j = 0; j < 8; j++)
          acc[i][j] = fmaf(av[i], bv8[j], acc[i][j]);
    }
  }

  float bb[8];
#pragma unroll
  for (int j = 0; j < 8; j++) bb[j] = bias[n0 + tn + j];

  if (zi < 2) {
    // row-major [b*s][h]
#pragma unroll
    for (int i = 0; i < 8; i++) {
      half8_t h;
#pragma unroll
      for (int j = 0; j < 8; j++) h[j] = (half_t)((acc[i][j] + bb[j]) * oscale);
      *(half8_t*)&out[(size_t)(m0 + tm + i) * 1024 + n0 + tn] = h;
    }
  } else {
    // V transposed: vt[b][h][s]
    const int bidx = m0 >> 12;
    const int s0 = (m0 & 4095) + tm;
#pragma unroll
    for (int j = 0; j < 8; j++) {
      half8_t h;
#pragma unroll
      for (int i = 0; i < 8; i++) h[i] = (half_t)(acc[i][j] + bb[j]);
      *(half8_t*)&out[((size_t)bidx * 1024 + (n0 + tn + j)) * 4096 + s0] = h;
    }
  }
}

// ---------------------------------------------------------------------------
// Kernel 2: MFMA flash attention.
// 256 threads = 4 waves. TQ=32 q-rows/block, TK=128 kv per iteration.
// Q fp16 resident in LDS; K read direct from global (B-fragment layout);
// V read direct from global vt[b][h][s]; P via LDS fp16 for A-operand.
// Softmax stats via shfl_xor within 16-lane C-layout groups.
// ---------------------------------------------------------------------------
#define TQ 32
#define TK 128
#define QSTR 1032  // halves; 2064 B rows, 16B aligned
#define PSTR 136   // halves; 272 B rows

#define MFMA16(a, b, c) __builtin_amdgcn_mfma_f32_16x16x32_f16(a, b, c, 0, 0, 0)

__global__ __launch_bounds__(256, 2) void flash_attn(
    const half_t* __restrict__ qw, const half_t* __restrict__ kw,
    const half_t* __restrict__ vt, float* __restrict__ out) {
  // XCD swizzle: batch b -> XCD slots {2b, 2b+1}; 64 blocks per XCD share
  // the same K/V stream for L2 locality.
  const int slot = blockIdx.x & 7;
  const int b = slot >> 1;
  const int qb = ((blockIdx.x >> 3) << 1) | (slot & 1);
  const int q0 = qb * TQ;
  const int t = threadIdx.x;
  const int w = t >> 6;
  const int lane = t & 63;
  const int ln = lane & 15;
  const int quad = lane >> 4;

  __shared__ half_t Qs[TQ * QSTR];
  __shared__ half_t Ps[TQ * PSTR];
  __shared__ float wmax[4][32];
  __shared__ float wl[4][32];
  __shared__ float mS[32], lS[32], aS[32];

  const half_t* qp = qw + ((size_t)b * S_LEN + q0) * H_DIM;
  const half_t* kb = kw + (size_t)b * S_LEN * H_DIM;
  const half_t* vbt = vt + (size_t)b * H_DIM * S_LEN;

  // stage Q tile (pre-scaled by 1/32)
#pragma unroll
  for (int i = 0; i < 16; i++) {
    int flat = t * 8 + i * 2048;
    int r = flat >> 10, c = flat & 1023;
    *(half8_t*)&Qs[r * QSTR + c] = *(const half8_t*)&qp[(size_t)r * H_DIM + c];
  }
  if (t < 32) {
    mS[t] = -1e30f;
    lS[t] = 0.0f;
  }
  __syncthreads();

  float4_t O[2][16] = {};

  const half_t* q0p = Qs + ln * QSTR + quad * 8;
  const half_t* q1p = q0p + 16 * QSTR;

  for (int kt = 0; kt < S_LEN; kt += TK) {
    // ---------------- phase A: S = Q . K^T (fp32 acc) ----------------
    float4_t s00 = {0.f, 0.f, 0.f, 0.f}, s01 = s00, s10 = s00, s11 = s00;
    const half_t* kr0 = kb + (size_t)(kt + w * 32 + ln) * H_DIM + quad * 8;
    const half_t* kr1 = kr0 + (size_t)16 * H_DIM;
    half8_t kb0[4], kb1[4];
#pragma unroll
    for (int d = 0; d < 4; d++) {
      kb0[d] = *(const half8_t*)(kr0 + d * 32);
      kb1[d] = *(const half8_t*)(kr1 + d * 32);
    }
#pragma unroll
    for (int ks = 0; ks < 32; ks++) {
      half8_t a0 = *(const half8_t*)(q0p + ks * 32);
      half8_t a1 = *(const half8_t*)(q1p + ks * 32);
      half8_t c0 = kb0[ks & 3], c1 = kb1[ks & 3];
      if (ks < 28) {
        kb0[ks & 3] = *(const half8_t*)(kr0 + (ks + 4) * 32);
        kb1[ks & 3] = *(const half8_t*)(kr1 + (ks + 4) * 32);
      }
      s00 = MFMA16(a0, c0, s00);
      s01 = MFMA16(a0, c1, s01);
      s10 = MFMA16(a1, c0, s10);
      s11 = MFMA16(a1, c1, s11);
    }

    // ---------------- softmax stats (C layout: row=quad*4+r, col=ln) ------
    float rm0[4], rm1[4];
#pragma unroll
    for (int r = 0; r < 4; r++) {
      rm0[r] = fmaxf(s00[r], s01[r]);
      rm1[r] = fmaxf(s10[r], s11[r]);
    }
#pragma unroll
    for (int off = 1; off < 16; off <<= 1)
#pragma unroll
      for (int r = 0; r < 4; r++) {
        rm0[r] = fmaxf(rm0[r], __shfl_xor(rm0[r], off));
        rm1[r] = fmaxf(rm1[r], __shfl_xor(rm1[r], off));
      }
    if (ln == 0)
#pragma unroll
      for (int r = 0; r < 4; r++) {
        wmax[w][quad * 4 + r] = rm0[r];
        wmax[w][16 + quad * 4 + r] = rm1[r];
      }
    __syncthreads();  // W1
    if (t < 32) {
      float nm = fmaxf(fmaxf(wmax[0][t], wmax[1][t]),
                       fmaxf(wmax[2][t], wmax[3][t]));
      nm = fmaxf(nm, mS[t]);
      aS[t] = __expf(mS[t] - nm);
      mS[t] = nm;
    }
    __syncthreads();  // W2

    // ---------------- P = exp(S - m), fp16 to LDS, partial row sums -------
    float nm0[4], nm1[4];
#pragma unroll
    for (int r = 0; r < 4; r++) {
      nm0[r] = mS[quad * 4 + r];
      nm1[r] = mS[16 + quad * 4 + r];
    }
    float pl0[4], pl1[4];
#pragma unroll
    for (int r = 0; r < 4; r++) {
      float p00 = __expf(s00[r] - nm0[r]);
      float p01 = __expf(s01[r] - nm0[r]);
      float p10 = __expf(s10[r] - nm1[r]);
      float p11 = __expf(s11[r] - nm1[r]);
      pl0[r] = p00 + p01;
      pl1[r] = p10 + p11;
      Ps[(quad * 4 + r) * PSTR + w * 32 + ln] = (half_t)p00;
      Ps[(quad * 4 + r) * PSTR + w * 32 + 16 + ln] = (half_t)p01;
      Ps[(16 + quad * 4 + r) * PSTR + w * 32 + ln] = (half_t)p10;
      Ps[(16 + quad * 4 + r) * PSTR + w * 32 + 16 + ln] = (half_t)p11;
    }
#pragma unroll
    for (int off = 1; off < 16; off <<= 1)
#pragma unroll
      for (int r = 0; r < 4; r++) {
        pl0[r] += __shfl_xor(pl0[r], off);
        pl1[r] += __shfl_xor(pl1[r], off);
      }
    if (ln == 0)
#pragma unroll
      for (int r = 0; r < 4; r++) {
        wl[w][quad * 4 + r] = pl0[r];
        wl[w][16 + quad * 4 + r] = pl1[r];
      }
    __syncthreads();  // W3
    if (t < 32)
      lS[t] = lS[t] * aS[t] + (wl[0][t] + wl[1][t] + wl[2][t] + wl[3][t]);

    // ---------------- rescale O by alpha ----------------
    float al0[4], al1[4];
#pragma unroll
    for (int r = 0; r < 4; r++) {
      al0[r] = aS[quad * 4 + r];
      al1[r] = aS[16 + quad * 4 + r];
    }
#pragma unroll
    for (int j = 0; j < 16; j++)
#pragma unroll
      for (int r = 0; r < 4; r++) {
        O[0][j][r] *= al0[r];
        O[1][j][r] *= al1[r];
      }

    // ---------------- phase C: O += P @ V ----------------
    half8_t pa0[4], pa1[4];
#pragma unroll
    for (int k = 0; k < 4; k++) {
      pa0[k] = *(const half8_t*)(Ps + ln * PSTR + k * 32 + quad * 8);
      pa1[k] = *(const half8_t*)(Ps + (16 + ln) * PSTR + k * 32 + quad * 8);
    }
    const half_t* vbase = vbt + (size_t)(w * 256 + ln) * S_LEN + kt + quad * 8;
    half8_t vbuf[2][4];
#pragma unroll
    for (int k = 0; k < 4; k++) vbuf[0][k] = *(const half8_t*)(vbase + k * 32);
#pragma unroll
    for (int j = 0; j < 16; j++) {
      if (j < 15)
#pragma unroll
        for (int k = 0; k < 4; k++)
          vbuf[(j + 1) & 1][k] =
              *(const half8_t*)(vbase + (size_t)(j + 1) * 16 * S_LEN + k * 32);
#pragma unroll
      for (int k = 0; k < 4; k++) {
        O[0][j] = MFMA16(pa0[k], vbuf[j & 1][k], O[0][j]);
        O[1][j] = MFMA16(pa1[k], vbuf[j & 1][k], O[1][j]);
      }
    }
  }

  // ---------------- epilogue: normalize, store fp32 ----------------
  __syncthreads();  // final lS ready
  float il0[4], il1[4];
#pragma unroll
  for (int r = 0; r < 4; r++) {
    il0[r] = 1.0f / lS[quad * 4 + r];
    il1[r] = 1.0f / lS[16 + quad * 4 + r];
  }
  float* ob = out + ((size_t)b * S_LEN + q0) * H_DIM + w * 256 + ln;
#pragma unroll
  for (int j = 0; j < 16; j++)
#pragma unroll
    for (int r = 0; r < 4; r++) {
      ob[(size_t)(quad * 4 + r) * H_DIM + j * 16] = O[0][j][r] * il0[r];
      ob[(size_t)(16 + quad * 4 + r) * H_DIM + j * 16] = O[1][j][r] * il1[r];
    }
}

// ---------------------------------------------------------------------------
extern "C" void kernel_launch(void* const* d_in, const int* in_sizes, int n_in,
                              void* d_out, int out_size, void* d_ws,
                              size_t ws_size, hipStream_t stream) {
  const float* x = (const float*)d_in[0];
  const float* Wq = (const float*)d_in[1];
  const float* bq = (const float*)d_in[2];
  const float* Wk = (const float*)d_in[3];
  const float* bk = (const float*)d_in[4];
  const float* Wv = (const float*)d_in[5];
  const float* bv = (const float*)d_in[6];
  half_t* ws = (half_t*)d_ws;  // q(32MB) | k(32MB) | vt(32MB, transposed)
  float* out = (float*)d_out;

  qkv_gemm<<<dim3(H_DIM / G_TILE, (NB * S_LEN) / G_TILE, 3), 256, 0, stream>>>(
      x, Wq, bq, Wk, bk, Wv, bv, ws);

  const half_t* qw = ws;
  const half_t* kw = ws + (size_t)NB * S_LEN * H_DIM;
  const half_t* vt = ws + 2 * (size_t)NB * S_LEN * H_DIM;
  flash_attn<<<dim3((S_LEN / TQ) * NB), 256, 0, stream>>>(qw, kw, vt, out);
}

// Round 3
// 1420.407 us; speedup vs baseline: 4.0993x; 1.5793x over previous
//
#include <hip/hip_runtime.h>

typedef _Float16 half_t;
typedef _Float16 half4_t __attribute__((ext_vector_type(4)));
typedef _Float16 half8_t __attribute__((ext_vector_type(8)));
typedef float float4_t __attribute__((ext_vector_type(4)));

#define S_LEN 4096
#define NB 4
#define H_DIM 1024

#define MFMA16(a, b, c) __builtin_amdgcn_mfma_f32_16x16x32_f16(a, b, c, 0, 0, 0)

// ---------------------------------------------------------------------------
// Kernel 0: transpose + fp16-split W -> Wt_hi/Wt_lo [h][f], stored in d_out
// scratch region (flash_attn overwrites all of d_out afterwards).
// ---------------------------------------------------------------------------
__global__ __launch_bounds__(256) void wt_prep(
    const float* __restrict__ Wq, const float* __restrict__ Wk,
    const float* __restrict__ Wv, half_t* __restrict__ wth,
    half_t* __restrict__ wtl) {
  const int zi = blockIdx.z;
  const float* W = (zi == 0) ? Wq : (zi == 1) ? Wk : Wv;
  half_t* oh = wth + (size_t)zi * H_DIM * H_DIM;
  half_t* ol = wtl + (size_t)zi * H_DIM * H_DIM;
  const int h0 = blockIdx.x * 32, f0 = blockIdx.y * 32;
  __shared__ float Ws[32][33];
  const int t = threadIdx.x;
  const int c = t & 31, r8 = t >> 5;
#pragma unroll
  for (int rr = 0; rr < 4; rr++)
    Ws[r8 * 4 + rr][c] = W[(size_t)(f0 + r8 * 4 + rr) * H_DIM + h0 + c];
  __syncthreads();
#pragma unroll
  for (int rr = 0; rr < 4; rr++) {
    int h = r8 * 4 + rr;
    float v = Ws[c][h];  // = W[f0+c][h0+h]
    half_t hi = (half_t)v;
    half_t lo = (half_t)(v - (float)hi);
    oh[(size_t)(h0 + h) * H_DIM + f0 + c] = hi;
    ol[(size_t)(h0 + h) * H_DIM + f0 + c] = lo;
  }
}

// ---------------------------------------------------------------------------
// Kernel 1: QKV projection on MFMA, 3-term fp16 split (hh + lh + hl),
// fp32 accumulate.  A = Wt (m=h), B = x (n=s, split on the fly into LDS).
// Tile 128(h) x 128(s), BK=64, 4 waves.  q pre-scaled by 1/32; V stored
// transposed vt[b][h][s].
// ---------------------------------------------------------------------------
#define QKV_BK 64

__global__ __launch_bounds__(256, 2) void qkv_mfma(
    const float* __restrict__ x, const half_t* __restrict__ wth,
    const half_t* __restrict__ wtl, const float* __restrict__ bq,
    const float* __restrict__ bk, const float* __restrict__ bv,
    half_t* __restrict__ ws) {
  const int zi = blockIdx.z;
  const half_t* Ah_g = wth + (size_t)zi * H_DIM * H_DIM;
  const half_t* Al_g = wtl + (size_t)zi * H_DIM * H_DIM;
  const float* bias = (zi == 0) ? bq : (zi == 1) ? bk : bv;
  half_t* out = ws + (size_t)zi * ((size_t)NB * S_LEN * H_DIM);
  const int m0 = blockIdx.x * 128;  // h
  const int n0 = blockIdx.y * 128;  // flattened b*s
  const int t = threadIdx.x;
  const int w = t >> 6, lane = t & 63, ln = lane & 15, quad = lane >> 4;

  // [split(2)][k2(2)][nt(8)][lane(64)][8] halves = 32 KB
  __shared__ half_t Bs[16384];

  float4_t acc[2][8] = {};

  const int ss = t >> 1;  // s-local 0..127
  const int fh = (t & 1) * 32;
  const int snt = ss >> 4, sln = ss & 15;

  for (int k0 = 0; k0 < H_DIM; k0 += QKV_BK) {
    // A-frags (Wt hi/lo) direct from global (L2-hot, 4 MB reused by all)
    half8_t ah[2][2], al[2][2];  // [m-tile][k2]
#pragma unroll
    for (int i = 0; i < 2; i++) {
      const size_t arow =
          (size_t)(m0 + w * 32 + i * 16 + ln) * H_DIM + k0 + quad * 8;
#pragma unroll
      for (int k2 = 0; k2 < 2; k2++) {
        ah[i][k2] = *(const half8_t*)(Ah_g + arow + k2 * 32);
        al[i][k2] = *(const half8_t*)(Al_g + arow + k2 * 32);
      }
    }
    __syncthreads();  // previous-iter LDS readers done
    // stage x[n0..n0+127][k0+fh..+31] -> hi/lo fragment order
    {
      const float* xp = x + (size_t)(n0 + ss) * H_DIM + k0 + fh;
#pragma unroll
      for (int g = 0; g < 4; g++) {
        float4 v0 = *(const float4*)(xp + g * 8);
        float4 v1 = *(const float4*)(xp + g * 8 + 4);
        float vv[8] = {v0.x, v0.y, v0.z, v0.w, v1.x, v1.y, v1.z, v1.w};
        half8_t hhi, hlo;
#pragma unroll
        for (int j = 0; j < 8; j++) {
          half_t h = (half_t)vv[j];
          hhi[j] = h;
          hlo[j] = (half_t)(vv[j] - (float)h);
        }
        int f = fh + g * 8;
        int k2 = f >> 5, qd = (f >> 3) & 3;
        int base = ((k2 * 8 + snt) * 64 + qd * 16 + sln) * 8;
        *(half8_t*)&Bs[base] = hhi;
        *(half8_t*)&Bs[8192 + base] = hlo;
      }
    }
    __syncthreads();
#pragma unroll
    for (int k2 = 0; k2 < 2; k2++) {
#pragma unroll
      for (int nt = 0; nt < 8; nt++) {
        int base = ((k2 * 8 + nt) * 64 + lane) * 8;
        half8_t bh = *(const half8_t*)&Bs[base];
        half8_t bl = *(const half8_t*)&Bs[8192 + base];
        acc[0][nt] = MFMA16(ah[0][k2], bh, acc[0][nt]);
        acc[1][nt] = MFMA16(ah[1][k2], bh, acc[1][nt]);
        acc[0][nt] = MFMA16(al[0][k2], bh, acc[0][nt]);
        acc[1][nt] = MFMA16(al[1][k2], bh, acc[1][nt]);
        acc[0][nt] = MFMA16(ah[0][k2], bl, acc[0][nt]);
        acc[1][nt] = MFMA16(ah[1][k2], bl, acc[1][nt]);
      }
    }
  }

  // epilogue.  C layout: col=ln -> s, row=quad*4+r -> h.
  const float oscale = (zi == 0) ? 0.03125f : 1.0f;
  float bb[2][4];
#pragma unroll
  for (int i = 0; i < 2; i++)
#pragma unroll
    for (int r = 0; r < 4; r++)
      bb[i][r] = bias[m0 + w * 32 + i * 16 + quad * 4 + r];

  if (zi < 2) {
#pragma unroll
    for (int i = 0; i < 2; i++)
#pragma unroll
      for (int nt = 0; nt < 8; nt++) {
        half4_t h4;
#pragma unroll
        for (int r = 0; r < 4; r++)
          h4[r] = (half_t)((acc[i][nt][r] + bb[i][r]) * oscale);
        size_t s = n0 + nt * 16 + ln;
        *(half4_t*)&out[s * H_DIM + m0 + w * 32 + i * 16 + quad * 4] = h4;
      }
  } else {
    // vt[b][h][s]
#pragma unroll
    for (int i = 0; i < 2; i++)
#pragma unroll
      for (int nt = 0; nt < 8; nt++) {
        int sf = n0 + nt * 16 + ln;
        int b = sf >> 12, si = sf & 4095;
#pragma unroll
        for (int r = 0; r < 4; r++) {
          int h = m0 + w * 32 + i * 16 + quad * 4 + r;
          out[((size_t)b * H_DIM + h) * S_LEN + si] =
              (half_t)(acc[i][nt][r] + bb[i][r]);
        }
      }
  }
}

// ---------------------------------------------------------------------------
// Kernel 2: MFMA flash attention.  TQ=32 q-rows/block, TK=128 kv/iter.
// Qs & Ps in fragment order (conflict-free ds_read_b128, zero addr math).
// K ring depth 6/rowset (12 outstanding), V ring 3 j-steps issued before
// softmax.  2 blocks/CU (73.5 KB LDS).
// ---------------------------------------------------------------------------
#define TQ 32
#define TK 128

__global__ __launch_bounds__(256, 2) void flash_attn(
    const half_t* __restrict__ qw, const half_t* __restrict__ kw,
    const half_t* __restrict__ vt, float* __restrict__ out) {
  const int slot = blockIdx.x & 7;
  const int b = slot >> 1;
  const int qb = ((blockIdx.x >> 3) << 1) | (slot & 1);
  const int q0 = qb * TQ;
  const int t = threadIdx.x;
  const int w = t >> 6;
  const int lane = t & 63;
  const int ln = lane & 15;
  const int quad = lane >> 4;

  __shared__ half_t Qs[32768];  // [set(2)][ks(32)][lane(64)][8] = 64 KB
  __shared__ half_t Ps[4096];   // [set(2)][kc(4)][lane(64)][8] = 8 KB
  __shared__ float wmax[4][32];
  __shared__ float wl[4][32];
  __shared__ float mS[32], lS[32], aS[32];

  const half_t* qp = qw + ((size_t)b * S_LEN + q0) * H_DIM;
  const half_t* kb = kw + (size_t)b * S_LEN * H_DIM;
  const half_t* vbt = vt + (size_t)b * H_DIM * S_LEN;

  // stage Q tile into fragment order
#pragma unroll
  for (int i = 0; i < 16; i++) {
    int flat = t * 8 + i * 2048;
    int r = flat >> 10, c = flat & 1023;
    int set = r >> 4, lq = r & 15, ks = c >> 5, qd = (c >> 3) & 3;
    *(half8_t*)&Qs[((set * 32 + ks) * 64 + qd * 16 + lq) * 8] =
        *(const half8_t*)&qp[(size_t)r * H_DIM + c];
  }
  if (t < 32) {
    mS[t] = -1e30f;
    lS[t] = 0.0f;
  }
  __syncthreads();

  float4_t O[2][16] = {};

  for (int kt = 0; kt < S_LEN; kt += TK) {
    // ---------------- phase A: S = Q . K^T ----------------
    float4_t s00 = {0.f, 0.f, 0.f, 0.f}, s01 = s00, s10 = s00, s11 = s00;
    const half_t* kr0 = kb + (size_t)(kt + w * 32 + ln) * H_DIM + quad * 8;
    const half_t* kr1 = kr0 + (size_t)16 * H_DIM;
    half8_t kb0[6], kb1[6];
#pragma unroll
    for (int d = 0; d < 6; d++) {
      kb0[d] = *(const half8_t*)(kr0 + d * 32);
      kb1[d] = *(const half8_t*)(kr1 + d * 32);
    }
#pragma unroll
    for (int ks = 0; ks < 32; ks++) {
      half8_t a0 = *(const half8_t*)&Qs[(ks * 64 + lane) * 8];
      half8_t a1 = *(const half8_t*)&Qs[16384 + (ks * 64 + lane) * 8];
      half8_t c0 = kb0[ks % 6], c1 = kb1[ks % 6];
      if (ks < 26) {
        kb0[ks % 6] = *(const half8_t*)(kr0 + (ks + 6) * 32);
        kb1[ks % 6] = *(const half8_t*)(kr1 + (ks + 6) * 32);
      }
      s00 = MFMA16(a0, c0, s00);
      s01 = MFMA16(a0, c1, s01);
      s10 = MFMA16(a1, c0, s10);
      s11 = MFMA16(a1, c1, s11);
    }

    // early V prefetch (independent of softmax; hides L2 latency under it)
    const half_t* vbase =
        vbt + (size_t)(w * 256 + ln) * S_LEN + kt + quad * 8;
    half8_t vbuf[3][4];
#pragma unroll
    for (int d = 0; d < 2; d++)
#pragma unroll
      for (int kc = 0; kc < 4; kc++)
        vbuf[d][kc] =
            *(const half8_t*)(vbase + (size_t)d * 16 * S_LEN + kc * 32);

    // ---------------- softmax stats (C layout: q=quad*4+r, kv=w*32+ln) ----
    float rm0[4], rm1[4];
#pragma unroll
    for (int r = 0; r < 4; r++) {
      rm0[r] = fmaxf(s00[r], s01[r]);
      rm1[r] = fmaxf(s10[r], s11[r]);
    }
#pragma unroll
    for (int off = 1; off < 16; off <<= 1)
#pragma unroll
      for (int r = 0; r < 4; r++) {
        rm0[r] = fmaxf(rm0[r], __shfl_xor(rm0[r], off));
        rm1[r] = fmaxf(rm1[r], __shfl_xor(rm1[r], off));
      }
    if (ln == 0)
#pragma unroll
      for (int r = 0; r < 4; r++) {
        wmax[w][quad * 4 + r] = rm0[r];
        wmax[w][16 + quad * 4 + r] = rm1[r];
      }
    __syncthreads();  // W1
    if (t < 32) {
      float nm = fmaxf(fmaxf(wmax[0][t], wmax[1][t]),
                       fmaxf(wmax[2][t], wmax[3][t]));
      nm = fmaxf(nm, mS[t]);
      aS[t] = __expf(mS[t] - nm);
      mS[t] = nm;
    }
    __syncthreads();  // W2

    // ---------------- P = exp(S - m) -> Ps (fragment order) ---------------
    float nm0[4], nm1[4];
#pragma unroll
    for (int r = 0; r < 4; r++) {
      nm0[r] = mS[quad * 4 + r];
      nm1[r] = mS[16 + quad * 4 + r];
    }
    const int jbit = ln & 7;
    const int qb8 = ln >> 3;  // 0/1
    float pl0[4], pl1[4];
#pragma unroll
    for (int r = 0; r < 4; r++) {
      float p00 = __expf(s00[r] - nm0[r]);
      float p01 = __expf(s01[r] - nm0[r]);
      float p10 = __expf(s10[r] - nm1[r]);
      float p11 = __expf(s11[r] - nm1[r]);
      pl0[r] = p00 + p01;
      pl1[r] = p10 + p11;
      int q = quad * 4 + r;
      // halfidx = set*2048 + w*512 + qd*128 + q*8 + jbit
      Ps[w * 512 + qb8 * 128 + q * 8 + jbit] = (half_t)p00;
      Ps[w * 512 + (2 + qb8) * 128 + q * 8 + jbit] = (half_t)p01;
      Ps[2048 + w * 512 + qb8 * 128 + q * 8 + jbit] = (half_t)p10;
      Ps[2048 + w * 512 + (2 + qb8) * 128 + q * 8 + jbit] = (half_t)p11;
    }
#pragma unroll
    for (int off = 1; off < 16; off <<= 1)
#pragma unroll
      for (int r = 0; r < 4; r++) {
        pl0[r] += __shfl_xor(pl0[r], off);
        pl1[r] += __shfl_xor(pl1[r], off);
      }
    if (ln == 0)
#pragma unroll
      for (int r = 0; r < 4; r++) {
        wl[w][quad * 4 + r] = pl0[r];
        wl[w][16 + quad * 4 + r] = pl1[r];
      }
    __syncthreads();  // W3
    if (t < 32)
      lS[t] = lS[t] * aS[t] + (wl[0][t] + wl[1][t] + wl[2][t] + wl[3][t]);

    // ---------------- rescale O by alpha ----------------
    float al0[4], al1[4];
#pragma unroll
    for (int r = 0; r < 4; r++) {
      al0[r] = aS[quad * 4 + r];
      al1[r] = aS[16 + quad * 4 + r];
    }
#pragma unroll
    for (int j = 0; j < 16; j++)
#pragma unroll
      for (int r = 0; r < 4; r++) {
        O[0][j][r] *= al0[r];
        O[1][j][r] *= al1[r];
      }

    // ---------------- phase C: O += P @ V ----------------
    half8_t pa0[4], pa1[4];
#pragma unroll
    for (int kc = 0; kc < 4; kc++) {
      pa0[kc] = *(const half8_t*)&Ps[(kc * 64 + lane) * 8];
      pa1[kc] = *(const half8_t*)&Ps[2048 + (kc * 64 + lane) * 8];
    }
#pragma unroll
    for (int j = 0; j < 16; j++) {
      if (j < 14)
#pragma unroll
        for (int kc = 0; kc < 4; kc++)
          vbuf[(j + 2) % 3][kc] = *(const half8_t*)(vbase +
              (size_t)(j + 2) * 16 * S_LEN + kc * 32);
#pragma unroll
      for (int kc = 0; kc < 4; kc++) {
        O[0][j] = MFMA16(pa0[kc], vbuf[j % 3][kc], O[0][j]);
        O[1][j] = MFMA16(pa1[kc], vbuf[j % 3][kc], O[1][j]);
      }
    }
  }

  // ---------------- epilogue ----------------
  __syncthreads();
  float il0[4], il1[4];
#pragma unroll
  for (int r = 0; r < 4; r++) {
    il0[r] = 1.0f / lS[quad * 4 + r];
    il1[r] = 1.0f / lS[16 + quad * 4 + r];
  }
  float* ob = out + ((size_t)b * S_LEN + q0) * H_DIM + w * 256 + ln;
#pragma unroll
  for (int j = 0; j < 16; j++)
#pragma unroll
    for (int r = 0; r < 4; r++) {
      ob[(size_t)(quad * 4 + r) * H_DIM + j * 16] = O[0][j][r] * il0[r];
      ob[(size_t)(16 + quad * 4 + r) * H_DIM + j * 16] = O[1][j][r] * il1[r];
    }
}

// ---------------------------------------------------------------------------
extern "C" void kernel_launch(void* const* d_in, const int* in_sizes, int n_in,
                              void* d_out, int out_size, void* d_ws,
                              size_t ws_size, hipStream_t stream) {
  const float* x = (const float*)d_in[0];
  const float* Wq = (const float*)d_in[1];
  const float* bq = (const float*)d_in[2];
  const float* Wk = (const float*)d_in[3];
  const float* bk = (const float*)d_in[4];
  const float* Wv = (const float*)d_in[5];
  const float* bv = (const float*)d_in[6];
  half_t* ws = (half_t*)d_ws;  // q(32MB) | k(32MB) | vt(32MB, transposed)
  float* out = (float*)d_out;

  // Wt scratch lives in d_out's first 12 MB; flash_attn overwrites all of
  // d_out afterwards, so final output is untouched by this.
  half_t* wth = (half_t*)d_out;
  half_t* wtl = wth + (size_t)3 * H_DIM * H_DIM;

  wt_prep<<<dim3(32, 32, 3), 256, 0, stream>>>(Wq, Wk, Wv, wth, wtl);

  qkv_mfma<<<dim3(8, 128, 3), 256, 0, stream>>>(x, wth, wtl, bq, bk, bv, ws);

  const half_t* qw = ws;
  const half_t* kw = ws + (size_t)NB * S_LEN * H_DIM;
  const half_t* vt = ws + 2 * (size_t)NB * S_LEN * H_DIM;
  flash_attn<<<dim3((S_LEN / TQ) * NB), 256, 0, stream>>>(qw, kw, vt, out);
}

// Round 4
// 1244.073 us; speedup vs baseline: 4.6803x; 1.1417x over previous
//
#include <hip/hip_runtime.h>

typedef _Float16 half_t;
typedef _Float16 half4_t __attribute__((ext_vector_type(4)));
typedef _Float16 half8_t __attribute__((ext_vector_type(8)));
typedef float float4_t __attribute__((ext_vector_type(4)));

#define S_LEN 4096
#define NB 4
#define H_DIM 1024

#define MFMA16(a, b, c) __builtin_amdgcn_mfma_f32_16x16x32_f16(a, b, c, 0, 0, 0)

// ---------------------------------------------------------------------------
// Kernel 0: transpose + fp16-split W -> Wt_hi/Wt_lo [h][f] (scratch in d_out;
// flash_attn overwrites all of d_out afterwards).
// ---------------------------------------------------------------------------
__global__ __launch_bounds__(256) void wt_prep(
    const float* __restrict__ Wq, const float* __restrict__ Wk,
    const float* __restrict__ Wv, half_t* __restrict__ wth,
    half_t* __restrict__ wtl) {
  const int zi = blockIdx.z;
  const float* W = (zi == 0) ? Wq : (zi == 1) ? Wk : Wv;
  half_t* oh = wth + (size_t)zi * H_DIM * H_DIM;
  half_t* ol = wtl + (size_t)zi * H_DIM * H_DIM;
  const int h0 = blockIdx.x * 32, f0 = blockIdx.y * 32;
  __shared__ float Ws[32][33];
  const int t = threadIdx.x;
  const int c = t & 31, r8 = t >> 5;
#pragma unroll
  for (int rr = 0; rr < 4; rr++)
    Ws[r8 * 4 + rr][c] = W[(size_t)(f0 + r8 * 4 + rr) * H_DIM + h0 + c];
  __syncthreads();
#pragma unroll
  for (int rr = 0; rr < 4; rr++) {
    int h = r8 * 4 + rr;
    float v = Ws[c][h];
    half_t hi = (half_t)v;
    half_t lo = (half_t)(v - (float)hi);
    oh[(size_t)(h0 + h) * H_DIM + f0 + c] = hi;
    ol[(size_t)(h0 + h) * H_DIM + f0 + c] = lo;
  }
}

// ---------------------------------------------------------------------------
// Kernel 1: QKV projection on MFMA, 3-term fp16 split (hh + lh + hl).
// (unchanged from round 3)
// ---------------------------------------------------------------------------
#define QKV_BK 64

__global__ __launch_bounds__(256, 2) void qkv_mfma(
    const float* __restrict__ x, const half_t* __restrict__ wth,
    const half_t* __restrict__ wtl, const float* __restrict__ bq,
    const float* __restrict__ bk, const float* __restrict__ bv,
    half_t* __restrict__ ws) {
  const int zi = blockIdx.z;
  const half_t* Ah_g = wth + (size_t)zi * H_DIM * H_DIM;
  const half_t* Al_g = wtl + (size_t)zi * H_DIM * H_DIM;
  const float* bias = (zi == 0) ? bq : (zi == 1) ? bk : bv;
  half_t* out = ws + (size_t)zi * ((size_t)NB * S_LEN * H_DIM);
  const int m0 = blockIdx.x * 128;  // h
  const int n0 = blockIdx.y * 128;  // flattened b*s
  const int t = threadIdx.x;
  const int w = t >> 6, lane = t & 63, ln = lane & 15, quad = lane >> 4;

  __shared__ half_t Bs[16384];

  float4_t acc[2][8] = {};

  const int ss = t >> 1;
  const int fh = (t & 1) * 32;
  const int snt = ss >> 4, sln = ss & 15;

  for (int k0 = 0; k0 < H_DIM; k0 += QKV_BK) {
    half8_t ah[2][2], al[2][2];
#pragma unroll
    for (int i = 0; i < 2; i++) {
      const size_t arow =
          (size_t)(m0 + w * 32 + i * 16 + ln) * H_DIM + k0 + quad * 8;
#pragma unroll
      for (int k2 = 0; k2 < 2; k2++) {
        ah[i][k2] = *(const half8_t*)(Ah_g + arow + k2 * 32);
        al[i][k2] = *(const half8_t*)(Al_g + arow + k2 * 32);
      }
    }
    __syncthreads();
    {
      const float* xp = x + (size_t)(n0 + ss) * H_DIM + k0 + fh;
#pragma unroll
      for (int g = 0; g < 4; g++) {
        float4 v0 = *(const float4*)(xp + g * 8);
        float4 v1 = *(const float4*)(xp + g * 8 + 4);
        float vv[8] = {v0.x, v0.y, v0.z, v0.w, v1.x, v1.y, v1.z, v1.w};
        half8_t hhi, hlo;
#pragma unroll
        for (int j = 0; j < 8; j++) {
          half_t h = (half_t)vv[j];
          hhi[j] = h;
          hlo[j] = (half_t)(vv[j] - (float)h);
        }
        int f = fh + g * 8;
        int k2 = f >> 5, qd = (f >> 3) & 3;
        int base = ((k2 * 8 + snt) * 64 + qd * 16 + sln) * 8;
        *(half8_t*)&Bs[base] = hhi;
        *(half8_t*)&Bs[8192 + base] = hlo;
      }
    }
    __syncthreads();
#pragma unroll
    for (int k2 = 0; k2 < 2; k2++) {
#pragma unroll
      for (int nt = 0; nt < 8; nt++) {
        int base = ((k2 * 8 + nt) * 64 + lane) * 8;
        half8_t bh = *(const half8_t*)&Bs[base];
        half8_t bl = *(const half8_t*)&Bs[8192 + base];
        acc[0][nt] = MFMA16(ah[0][k2], bh, acc[0][nt]);
        acc[1][nt] = MFMA16(ah[1][k2], bh, acc[1][nt]);
        acc[0][nt] = MFMA16(al[0][k2], bh, acc[0][nt]);
        acc[1][nt] = MFMA16(al[1][k2], bh, acc[1][nt]);
        acc[0][nt] = MFMA16(ah[0][k2], bl, acc[0][nt]);
        acc[1][nt] = MFMA16(ah[1][k2], bl, acc[1][nt]);
      }
    }
  }

  const float oscale = (zi == 0) ? 0.03125f : 1.0f;
  float bb[2][4];
#pragma unroll
  for (int i = 0; i < 2; i++)
#pragma unroll
    for (int r = 0; r < 4; r++)
      bb[i][r] = bias[m0 + w * 32 + i * 16 + quad * 4 + r];

  if (zi < 2) {
#pragma unroll
    for (int i = 0; i < 2; i++)
#pragma unroll
      for (int nt = 0; nt < 8; nt++) {
        half4_t h4;
#pragma unroll
        for (int r = 0; r < 4; r++)
          h4[r] = (half_t)((acc[i][nt][r] + bb[i][r]) * oscale);
        size_t s = n0 + nt * 16 + ln;
        *(half4_t*)&out[s * H_DIM + m0 + w * 32 + i * 16 + quad * 4] = h4;
      }
  } else {
#pragma unroll
    for (int i = 0; i < 2; i++)
#pragma unroll
      for (int nt = 0; nt < 8; nt++) {
        int sf = n0 + nt * 16 + ln;
        int b = sf >> 12, si = sf & 4095;
#pragma unroll
        for (int r = 0; r < 4; r++) {
          int h = m0 + w * 32 + i * 16 + quad * 4 + r;
          out[((size_t)b * H_DIM + h) * S_LEN + si] =
              (half_t)(acc[i][nt][r] + bb[i][r]);
        }
      }
  }
}

// ---------------------------------------------------------------------------
// Kernel 2: MFMA flash attention, TQ=64 (512 threads, 8 waves, 1 block/CU).
// Halves L2/L3 K+V traffic vs TQ=32 (the measured 8.8 TB/s cache-BW floor).
// QK^T: wave = (q-half, k-32-chunk); PV: wave = h-128-chunk (V disjoint per
// wave, P broadcast from LDS). Every K/V byte read exactly once per block.
// LDS: Qs 128 KB + Ps 16 KB (fragment order, conflict-free b128).
// ---------------------------------------------------------------------------
#define TQ 64
#define TK 128

__global__ __launch_bounds__(512, 2) void flash_attn(
    const half_t* __restrict__ qw, const half_t* __restrict__ kw,
    const half_t* __restrict__ vt, float* __restrict__ out) {
  // batch -> 2 XCDs; 32 blocks/XCD share one K/V stream, 1 block/CU.
  const int slot = blockIdx.x & 7;
  const int b = slot >> 1;
  const int qb = ((blockIdx.x >> 3) << 1) | (slot & 1);
  const int q0 = qb * TQ;
  const int t = threadIdx.x;
  const int w = t >> 6;
  const int lane = t & 63;
  const int ln = lane & 15;
  const int quad = lane >> 4;
  const int qh = w >> 2;  // q half (rows qh*32..+32) in phase A
  const int ct = w & 3;   // k col-chunk (32) in phase A

  __shared__ half_t Qs[65536];  // [rs(4)][ks(32)][lane(64)][8] = 128 KB
  __shared__ half_t Ps[8192];   // [rs(4)][kc(4)][lane(64)][8] = 16 KB
  __shared__ float wmax[8][32];
  __shared__ float wl[8][32];
  __shared__ float mS[64], lS[64], aS[64];

  const half_t* qp = qw + ((size_t)b * S_LEN + q0) * H_DIM;
  const half_t* kb = kw + (size_t)b * S_LEN * H_DIM;
  const half_t* vbt = vt + (size_t)b * H_DIM * S_LEN;

  // stage Q tile into fragment order
#pragma unroll
  for (int i = 0; i < 16; i++) {
    int flat = t * 8 + i * 4096;
    int r = flat >> 10, c = flat & 1023;
    int rs = r >> 4, lq = r & 15, ks = c >> 5, qd = (c >> 3) & 3;
    *(half8_t*)&Qs[((rs * 32 + ks) * 64 + qd * 16 + lq) * 8] =
        *(const half8_t*)&qp[(size_t)r * H_DIM + c];
  }
  if (t < 64) {
    mS[t] = -1e30f;
    lS[t] = 0.0f;
  }
  __syncthreads();

  float4_t O[4][8] = {};  // [rs(4 row-tiles)][j(8 col-tiles in h-chunk w)]

  const int qs0 = qh * 32768;  // rowset qh*2 base (half-index)
  const int qs1 = qs0 + 16384;

  for (int kt = 0; kt < S_LEN; kt += TK) {
    // ---------------- phase A: S = Q . K^T ----------------
    float4_t s00 = {0.f, 0.f, 0.f, 0.f}, s01 = s00, s10 = s00, s11 = s00;
    const half_t* kr0 = kb + (size_t)(kt + ct * 32 + ln) * H_DIM + quad * 8;
    const half_t* kr1 = kr0 + (size_t)16 * H_DIM;
    half8_t kb0[6], kb1[6];
#pragma unroll
    for (int d = 0; d < 6; d++) {
      kb0[d] = *(const half8_t*)(kr0 + d * 32);
      kb1[d] = *(const half8_t*)(kr1 + d * 32);
    }
#pragma unroll
    for (int ks = 0; ks < 32; ks++) {
      half8_t a0 = *(const half8_t*)&Qs[qs0 + (ks * 64 + lane) * 8];
      half8_t a1 = *(const half8_t*)&Qs[qs1 + (ks * 64 + lane) * 8];
      half8_t c0 = kb0[ks % 6], c1 = kb1[ks % 6];
      if (ks < 26) {
        kb0[ks % 6] = *(const half8_t*)(kr0 + (ks + 6) * 32);
        kb1[ks % 6] = *(const half8_t*)(kr1 + (ks + 6) * 32);
      }
      s00 = MFMA16(a0, c0, s00);
      s01 = MFMA16(a0, c1, s01);
      s10 = MFMA16(a1, c0, s10);
      s11 = MFMA16(a1, c1, s11);
    }

    // early V prefetch (u=0,1) — hides L2 latency under softmax
    const half_t* vbase = vbt + (size_t)(w * 128 + ln) * S_LEN + kt + quad * 8;
    half8_t vbuf[3][2];
#pragma unroll
    for (int u = 0; u < 2; u++)
#pragma unroll
      for (int c = 0; c < 2; c++)
        vbuf[u][c] =
            *(const half8_t*)(vbase + (size_t)u * 16 * S_LEN + c * 32);

    // ---------------- softmax stats ----------------
    float rm0[4], rm1[4];
#pragma unroll
    for (int r = 0; r < 4; r++) {
      rm0[r] = fmaxf(s00[r], s01[r]);
      rm1[r] = fmaxf(s10[r], s11[r]);
    }
#pragma unroll
    for (int off = 1; off < 16; off <<= 1)
#pragma unroll
      for (int r = 0; r < 4; r++) {
        rm0[r] = fmaxf(rm0[r], __shfl_xor(rm0[r], off));
        rm1[r] = fmaxf(rm1[r], __shfl_xor(rm1[r], off));
      }
    if (ln == 0)
#pragma unroll
      for (int r = 0; r < 4; r++) {
        wmax[w][quad * 4 + r] = rm0[r];
        wmax[w][16 + quad * 4 + r] = rm1[r];
      }
    __syncthreads();  // W1
    if (t < 64) {
      int g = (t >> 5) * 4, l32 = t & 31;
      float nm = fmaxf(fmaxf(wmax[g][l32], wmax[g + 1][l32]),
                       fmaxf(wmax[g + 2][l32], wmax[g + 3][l32]));
      nm = fmaxf(nm, mS[t]);
      aS[t] = __expf(mS[t] - nm);
      mS[t] = nm;
    }
    __syncthreads();  // W2

    // ---------------- P = exp(S - m) -> Ps (fragment order) ---------------
    float nm0[4], nm1[4];
#pragma unroll
    for (int r = 0; r < 4; r++) {
      nm0[r] = mS[qh * 32 + quad * 4 + r];
      nm1[r] = mS[qh * 32 + 16 + quad * 4 + r];
    }
    const int base00 =
        ((qh * 8 + ct) * 64 + (ln >> 3) * 16 + quad * 4) * 8 + (ln & 7);
    float pl0[4], pl1[4];
#pragma unroll
    for (int r = 0; r < 4; r++) {
      float p00 = __expf(s00[r] - nm0[r]);
      float p01 = __expf(s01[r] - nm0[r]);
      float p10 = __expf(s10[r] - nm1[r]);
      float p11 = __expf(s11[r] - nm1[r]);
      pl0[r] = p00 + p01;
      pl1[r] = p10 + p11;
      Ps[base00 + r * 8] = (half_t)p00;
      Ps[base00 + 256 + r * 8] = (half_t)p01;
      Ps[base00 + 2048 + r * 8] = (half_t)p10;
      Ps[base00 + 2304 + r * 8] = (half_t)p11;
    }
#pragma unroll
    for (int off = 1; off < 16; off <<= 1)
#pragma unroll
      for (int r = 0; r < 4; r++) {
        pl0[r] += __shfl_xor(pl0[r], off);
        pl1[r] += __shfl_xor(pl1[r], off);
      }
    if (ln == 0)
#pragma unroll
      for (int r = 0; r < 4; r++) {
        wl[w][quad * 4 + r] = pl0[r];
        wl[w][16 + quad * 4 + r] = pl1[r];
      }
    __syncthreads();  // W3
    if (t < 64) {
      int g = (t >> 5) * 4, l32 = t & 31;
      lS[t] = lS[t] * aS[t] +
              (wl[g][l32] + wl[g + 1][l32] + wl[g + 2][l32] + wl[g + 3][l32]);
    }

    // ---------------- rescale O by alpha ----------------
    float al[4][4];
#pragma unroll
    for (int rs = 0; rs < 4; rs++)
#pragma unroll
      for (int r = 0; r < 4; r++) al[rs][r] = aS[rs * 16 + quad * 4 + r];
#pragma unroll
    for (int rs = 0; rs < 4; rs++)
#pragma unroll
      for (int j = 0; j < 8; j++)
#pragma unroll
        for (int r = 0; r < 4; r++) O[rs][j][r] *= al[rs][r];

    // ---------------- phase C: O += P @ V ----------------
    half8_t pa[4][2];
#pragma unroll
    for (int u = 0; u < 16; u++) {
      const int kc2 = u >> 3, j = u & 7;
      if ((u & 7) == 0) {
#pragma unroll
        for (int rs = 0; rs < 4; rs++)
#pragma unroll
          for (int c = 0; c < 2; c++)
            pa[rs][c] =
                *(const half8_t*)&Ps[((rs * 4 + kc2 * 2 + c) * 64 + lane) * 8];
      }
      if (u < 14) {
        const int un = u + 2;
#pragma unroll
        for (int c = 0; c < 2; c++)
          vbuf[un % 3][c] = *(const half8_t*)(
              vbase + (size_t)(un & 7) * 16 * S_LEN +
              ((un >> 3) * 2 + c) * 32);
      }
#pragma unroll
      for (int c = 0; c < 2; c++)
#pragma unroll
        for (int rs = 0; rs < 4; rs++)
          O[rs][j] = MFMA16(pa[rs][c], vbuf[u % 3][c], O[rs][j]);
    }
  }

  // ---------------- epilogue ----------------
  __syncthreads();
  float il[4][4];
#pragma unroll
  for (int rs = 0; rs < 4; rs++)
#pragma unroll
    for (int r = 0; r < 4; r++) il[rs][r] = 1.0f / lS[rs * 16 + quad * 4 + r];
  float* ob = out + ((size_t)b * S_LEN + q0) * H_DIM + w * 128 + ln;
#pragma unroll
  for (int rs = 0; rs < 4; rs++)
#pragma unroll
    for (int j = 0; j < 8; j++)
#pragma unroll
      for (int r = 0; r < 4; r++)
        ob[(size_t)(rs * 16 + quad * 4 + r) * H_DIM + j * 16] =
            O[rs][j][r] * il[rs][r];
}

// ---------------------------------------------------------------------------
extern "C" void kernel_launch(void* const* d_in, const int* in_sizes, int n_in,
                              void* d_out, int out_size, void* d_ws,
                              size_t ws_size, hipStream_t stream) {
  const float* x = (const float*)d_in[0];
  const float* Wq = (const float*)d_in[1];
  const float* bq = (const float*)d_in[2];
  const float* Wk = (const float*)d_in[3];
  const float* bk = (const float*)d_in[4];
  const float* Wv = (const float*)d_in[5];
  const float* bv = (const float*)d_in[6];
  half_t* ws = (half_t*)d_ws;  // q(32MB) | k(32MB) | vt(32MB, transposed)
  float* out = (float*)d_out;

  half_t* wth = (half_t*)d_out;  // scratch; overwritten by flash_attn
  half_t* wtl = wth + (size_t)3 * H_DIM * H_DIM;

  wt_prep<<<dim3(32, 32, 3), 256, 0, stream>>>(Wq, Wk, Wv, wth, wtl);

  qkv_mfma<<<dim3(8, 128, 3), 256, 0, stream>>>(x, wth, wtl, bq, bk, bv, ws);

  const half_t* qw = ws;
  const half_t* kw = ws + (size_t)NB * S_LEN * H_DIM;
  const half_t* vt = ws + 2 * (size_t)NB * S_LEN * H_DIM;
  flash_attn<<<dim3((S_LEN / TQ) * NB), 512, 0, stream>>>(qw, kw, vt, out);
}